// Round 1
// baseline (202.902 us; speedup 1.0000x reference)
//
#include <hip/hip_runtime.h>
#include <float.h>

#define M_TOTAL 65536
#define DIMS 64
#define KC 1024
#define CS 4                 // codebook splits
#define CHUNK (KC / CS)      // 256 codes per split
#define TAU 4e-3f            // near-tie refinement margin (fp32 err ~3e-4)

// ---------------- ws layout (float elements) ----------------
// [0,1024)        se (codebook squared norms)
// [1024,1280)     partials (256 block loss sums)
// [4096, +CS*M)   min1
// next CS*M       min2
// next CS*M       idx (int)

__global__ __launch_bounds__(256) void k_se(const float* __restrict__ cb,
                                            float* __restrict__ se) {
  int k = blockIdx.x * 256 + threadIdx.x;
  const float4* p = (const float4*)(cb + (size_t)k * DIMS);
  float a0 = 0.f, a1 = 0.f, a2 = 0.f, a3 = 0.f;
#pragma unroll
  for (int i = 0; i < DIMS / 4; ++i) {
    float4 v = p[i];
    a0 = fmaf(v.x, v.x, a0);
    a1 = fmaf(v.y, v.y, a1);
    a2 = fmaf(v.z, v.z, a2);
    a3 = fmaf(v.w, v.w, a3);
  }
  se[k] = (a0 + a1) + (a2 + a3);
}

__global__ __launch_bounds__(256) void k_dist(const float* __restrict__ z,
                                              const float* __restrict__ cb,
                                              const float* __restrict__ se,
                                              float* __restrict__ min1o,
                                              float* __restrict__ min2o,
                                              int* __restrict__ idxo) {
  const int split = blockIdx.x & (CS - 1);
  const int rb = blockIdx.x >> 2;
  const int t = threadIdx.x;
  const int row = rb * 256 + t;

  // load z row to registers, compute ||z||^2
  float zr[DIMS];
  const float4* zp = (const float4*)(z + (size_t)row * DIMS);
  float s0 = 0.f, s1 = 0.f, s2 = 0.f, s3 = 0.f;
#pragma unroll
  for (int i = 0; i < DIMS / 4; ++i) {
    float4 v = zp[i];
    zr[4 * i + 0] = v.x;
    zr[4 * i + 1] = v.y;
    zr[4 * i + 2] = v.z;
    zr[4 * i + 3] = v.w;
    s0 = fmaf(v.x, v.x, s0);
    s1 = fmaf(v.y, v.y, s1);
    s2 = fmaf(v.z, v.z, s2);
    s3 = fmaf(v.w, v.w, s3);
  }
  const float sz = (s0 + s1) + (s2 + s3);

  float min1 = FLT_MAX, min2 = FLT_MAX;
  int bidx = 0;
  const int k0 = split * CHUNK;
  for (int kk = 0; kk < CHUNK; ++kk) {
    const int k = k0 + kk;
    // wave-uniform address -> scalar loads (SGPR operands in the FMAs)
    const float4* e4 = (const float4*)(cb + (size_t)k * DIMS);
    float d0 = 0.f, d1 = 0.f, d2 = 0.f, d3 = 0.f;
#pragma unroll
    for (int i = 0; i < DIMS / 4; ++i) {
      float4 e = e4[i];
      d0 = fmaf(zr[4 * i + 0], e.x, d0);
      d1 = fmaf(zr[4 * i + 1], e.y, d1);
      d2 = fmaf(zr[4 * i + 2], e.z, d2);
      d3 = fmaf(zr[4 * i + 3], e.w, d3);
    }
    float dist = fmaf(-2.f, (d0 + d1) + (d2 + d3), sz + se[k]);
    bool lt = dist < min1;
    min2 = fminf(min2, lt ? min1 : dist);
    bidx = lt ? k : bidx;
    min1 = lt ? dist : min1;
  }
  const int o = split * M_TOTAL + row;
  min1o[o] = min1;
  min2o[o] = min2;
  idxo[o] = bidx;
}

__global__ __launch_bounds__(256) void k_merge(const float* __restrict__ z,
                                               const float* __restrict__ cb,
                                               const float* __restrict__ min1i,
                                               const float* __restrict__ min2i,
                                               const int* __restrict__ idxi,
                                               float* __restrict__ out,
                                               float* __restrict__ partials) {
  const int rb = blockIdx.x;
  const int t = threadIdx.x;
  const int row = rb * 256 + t;

  __shared__ int s_idx[256];
  __shared__ int s_rows[256];
  __shared__ int s_n;
  __shared__ double s_rd[256];
  __shared__ int s_ri[256];
  __shared__ float s_sse[256];

  if (t == 0) s_n = 0;
  __syncthreads();

  // merge per-split (min1, min2, idx); splits in ascending code order so
  // strict '<' keeps the lowest index on exact ties (jnp.argmin semantics)
  float m1 = FLT_MAX, m2 = FLT_MAX;
  int bi = 0;
#pragma unroll
  for (int s = 0; s < CS; ++s) {
    float a1 = min1i[s * M_TOTAL + row];
    float a2 = min2i[s * M_TOTAL + row];
    int ai = idxi[s * M_TOTAL + row];
    if (a1 < m1) {
      m2 = fminf(m1, a2);
      m1 = a1;
      bi = ai;
    } else {
      m2 = fminf(m2, a1);
    }
  }
  s_idx[t] = bi;
  if (m2 - m1 < TAU) {  // near-tie: needs exact resolution
    int p = atomicAdd(&s_n, 1);
    s_rows[p] = t;
  }
  __syncthreads();

  // block-cooperative exact fp64 recompute for flagged rows (rare)
  const int nf = s_n;
  for (int f = 0; f < nf; ++f) {
    const int lrow = s_rows[f];
    const int frow = rb * 256 + lrow;
    const float* zz = z + (size_t)frow * DIMS;
    double best = 1e300;
    int bidx2 = 0;
    for (int c = t; c < KC; c += 256) {
      const float* e = cb + (size_t)c * DIMS;
      double acc = 0.0;
#pragma unroll
      for (int d = 0; d < DIMS; ++d) {
        double df = (double)zz[d] - (double)e[d];
        acc = fma(df, df, acc);
      }
      if (acc < best) {
        best = acc;
        bidx2 = c;
      }
    }
    s_rd[t] = best;
    s_ri[t] = bidx2;
    __syncthreads();
    for (int off = 128; off > 0; off >>= 1) {
      if (t < off) {
        double ob = s_rd[t + off];
        int oi = s_ri[t + off];
        if (ob < s_rd[t] || (ob == s_rd[t] && oi < s_ri[t])) {
          s_rd[t] = ob;
          s_ri[t] = oi;
        }
      }
      __syncthreads();
    }
    if (t == 0) s_idx[lrow] = s_ri[0];
    __syncthreads();
  }

  // gather + straight-through output (z + (e - z), matching ref rounding) + loss
  const int fi = s_idx[t];
  const float4* ep = (const float4*)(cb + (size_t)fi * DIMS);
  const float4* zp = (const float4*)(z + (size_t)row * DIMS);
  float4* op = (float4*)(out + (size_t)row * DIMS);
  float sse = 0.f;
#pragma unroll
  for (int i = 0; i < DIMS / 4; ++i) {
    float4 e = ep[i];
    float4 v = zp[i];
    float dx = e.x - v.x, dy = e.y - v.y, dz = e.z - v.z, dw = e.w - v.w;
    sse = fmaf(dx, dx, sse);
    sse = fmaf(dy, dy, sse);
    sse = fmaf(dz, dz, sse);
    sse = fmaf(dw, dw, sse);
    float4 o;
    o.x = v.x + dx;
    o.y = v.y + dy;
    o.z = v.z + dz;
    o.w = v.w + dw;
    op[i] = o;
  }

  s_sse[t] = sse;
  __syncthreads();
  for (int off = 128; off > 0; off >>= 1) {
    if (t < off) s_sse[t] += s_sse[t + off];
    __syncthreads();
  }
  if (t == 0) partials[rb] = s_sse[0];
}

__global__ __launch_bounds__(256) void k_loss(const float* __restrict__ partials,
                                              float* __restrict__ out) {
  __shared__ float sh[256];
  const int t = threadIdx.x;
  sh[t] = partials[t];
  __syncthreads();
  for (int off = 128; off > 0; off >>= 1) {
    if (t < off) sh[t] += sh[t + off];
    __syncthreads();
  }
  if (t == 0) {
    // (0.1*mse + mse) * 10 = 11 * SSE / (M*D)
    out[(size_t)M_TOTAL * DIMS] = sh[0] * (11.0f / (float)((size_t)M_TOTAL * DIMS));
  }
}

extern "C" void kernel_launch(void* const* d_in, const int* in_sizes, int n_in,
                              void* d_out, int out_size, void* d_ws, size_t ws_size,
                              hipStream_t stream) {
  const float* z = (const float*)d_in[0];
  const float* cb = (const float*)d_in[1];
  float* out = (float*)d_out;
  float* ws = (float*)d_ws;

  float* se = ws;                       // 1024
  float* partials = ws + 1024;          // 256
  float* min1 = ws + 4096;              // CS*M
  float* min2 = min1 + (size_t)CS * M_TOTAL;
  int* idx = (int*)(min2 + (size_t)CS * M_TOTAL);

  k_se<<<KC / 256, 256, 0, stream>>>(cb, se);
  k_dist<<<(M_TOTAL / 256) * CS, 256, 0, stream>>>(z, cb, se, min1, min2, idx);
  k_merge<<<M_TOTAL / 256, 256, 0, stream>>>(z, cb, min1, min2, idx, out, partials);
  k_loss<<<1, 256, 0, stream>>>(partials, out);
}